// Round 1
// baseline (230.254 us; speedup 1.0000x reference)
//
#include <hip/hip_runtime.h>

#define BB 2
#define CC 64
#define HH 128
#define WW 128
#define OC 64
// padded plane: 130x130, clamp hi = 129

struct Meta {
    int   i0, i1, i2, i3;   // corner indices into a 128x128 plane, -1 = zero (pad)
    int   dst;              // LDS dst: n*64 + pp   (same for sX and sW)
    int   wsrc;             // Wc src (channel-invariant part): oc*576 + n
    float w0, w1, w2, w3;   // bilinear weights lt, rb, lb, rt
};

__global__ __launch_bounds__(256) void dcn_fused(
    const float* __restrict__ x,
    const float* __restrict__ Wp,
    const float* __restrict__ bp,
    const float* __restrict__ Wc,
    float* __restrict__ out)
{
    __shared__ float s_part[4][64][18];
    __shared__ __align__(16) float sX[576];   // [n][pp]
    __shared__ __align__(16) float sW[576];   // [n][oc]

    const int t    = threadIdx.x;
    const int pos0 = blockIdx.x * 64;
    const int b    = pos0 >> 14;          // 16384 positions per batch
    const int i    = (pos0 >> 7) & 127;
    const int j0   = pos0 & 127;          // 0 or 64

    // ---------------- phase 0a: offset conv partials ----------------
    {
        const int wid = __builtin_amdgcn_readfirstlane(t >> 6);  // wave-uniform
        const int pp  = t & 63;
        const int j   = j0 + pp;
        float part[18];
#pragma unroll
        for (int o = 0; o < 18; ++o) part[o] = 0.f;
        const int c0 = wid << 4;
        for (int c = c0; c < c0 + 16; ++c) {
            const float* xc = x + (b * CC + c) * (HH * WW);
#pragma unroll
            for (int dx = 0; dx < 3; ++dx) {
                const int ii  = i + dx - 1;
                const bool okx = (unsigned)ii < (unsigned)HH;
#pragma unroll
                for (int dy = 0; dy < 3; ++dy) {
                    const int jj = j + dy - 1;
                    const bool ok = okx && ((unsigned)jj < (unsigned)WW);
                    const float xv = ok ? xc[ii * WW + jj] : 0.f;
                    const float* wp = Wp + c * 9 + dx * 3 + dy;  // wave-uniform addr
#pragma unroll
                    for (int o = 0; o < 18; ++o)
                        part[o] = fmaf(xv, wp[o * 576], part[o]);
                }
            }
        }
#pragma unroll
        for (int o = 0; o < 18; ++o) s_part[wid][pp][o] = part[o];
    }
    __syncthreads();

    // ---------------- phase 0b: per-thread sampling metadata ----------------
    auto compute_meta = [&](int e) -> Meta {
        Meta M;
        const int pp = e / 9;             // also plays the role of oc for sW staging
        const int n  = e - pp * 9;
        const int kx = n / 3;
        const int ky = n - kx * 3;
        float offx = bp[n];
        float offy = bp[9 + n];
#pragma unroll
        for (int wv = 0; wv < 4; ++wv) {
            offx += s_part[wv][pp][n];
            offy += s_part[wv][pp][9 + n];
        }
        const float px = offx + (float)(kx - 1) + (float)(i + 1);
        const float py = offy + (float)(ky - 1) + (float)(j0 + pp + 1);
        const float flx = floorf(px), fly = floorf(py);
        const float qltx = fminf(fmaxf(flx,       0.f), 129.f);
        const float qlty = fminf(fmaxf(fly,       0.f), 129.f);
        const float qrbx = fminf(fmaxf(flx + 1.f, 0.f), 129.f);
        const float qrby = fminf(fmaxf(fly + 1.f, 0.f), 129.f);
        const float pxc  = fminf(fmaxf(px, 0.f), 129.f);
        const float pyc  = fminf(fmaxf(py, 0.f), 129.f);
        const float gx0 = 1.f + (qltx - pxc);
        const float gx1 = 1.f - (qrbx - pxc);
        const float gy0 = 1.f + (qlty - pyc);
        const float gy1 = 1.f - (qrby - pyc);
        const int rx0 = (int)qltx - 1, rx1 = (int)qrbx - 1;
        const int ry0 = (int)qlty - 1, ry1 = (int)qrby - 1;
        const bool vx0 = (unsigned)rx0 < (unsigned)HH;
        const bool vx1 = (unsigned)rx1 < (unsigned)HH;
        const bool vy0 = (unsigned)ry0 < (unsigned)WW;
        const bool vy1 = (unsigned)ry1 < (unsigned)WW;
        M.i0 = (vx0 && vy0) ? rx0 * WW + ry0 : -1;  M.w0 = gx0 * gy0;  // lt
        M.i1 = (vx1 && vy1) ? rx1 * WW + ry1 : -1;  M.w1 = gx1 * gy1;  // rb
        M.i2 = (vx0 && vy1) ? rx0 * WW + ry1 : -1;  M.w2 = gx0 * gy1;  // lb
        M.i3 = (vx1 && vy0) ? rx1 * WW + ry0 : -1;  M.w3 = gx1 * gy0;  // rt
        M.dst  = n * 64 + pp;
        M.wsrc = pp * 576 + n;
        return M;
    };

    Meta M0 = compute_meta(t);
    Meta M1 = compute_meta(t + 256);
    Meta M2;
    const bool has2 = (t < 64);
    if (has2) { M2 = compute_meta(t + 512); }
    else { M2.i0 = M2.i1 = M2.i2 = M2.i3 = -1; M2.dst = 0; M2.wsrc = 0;
           M2.w0 = M2.w1 = M2.w2 = M2.w3 = 0.f; }

    // ---------------- main loop: stage + 64x64 outer-product GEMM ----------------
    float acc[4][4];
#pragma unroll
    for (int m = 0; m < 4; ++m)
#pragma unroll
        for (int p = 0; p < 4; ++p) acc[m][p] = 0.f;

    const int tm4 = (t >> 4) << 2;   // oc base (0..60)
    const int tp4 = (t & 15) << 2;   // pos base (0..60)
    const float* xb = x + b * (CC * HH * WW);

    for (int c = 0; c < CC; ++c) {
        const float* xc = xb + c * (HH * WW);
        const float* wc = Wc + c * 9;

        // stage sample values + weight tile
        {
            float v = 0.f;
            if (M0.i0 >= 0) v = fmaf(xc[M0.i0], M0.w0, v);
            if (M0.i1 >= 0) v = fmaf(xc[M0.i1], M0.w1, v);
            if (M0.i2 >= 0) v = fmaf(xc[M0.i2], M0.w2, v);
            if (M0.i3 >= 0) v = fmaf(xc[M0.i3], M0.w3, v);
            sX[M0.dst] = v;
            sW[M0.dst] = wc[M0.wsrc];
        }
        {
            float v = 0.f;
            if (M1.i0 >= 0) v = fmaf(xc[M1.i0], M1.w0, v);
            if (M1.i1 >= 0) v = fmaf(xc[M1.i1], M1.w1, v);
            if (M1.i2 >= 0) v = fmaf(xc[M1.i2], M1.w2, v);
            if (M1.i3 >= 0) v = fmaf(xc[M1.i3], M1.w3, v);
            sX[M1.dst] = v;
            sW[M1.dst] = wc[M1.wsrc];
        }
        if (has2) {
            float v = 0.f;
            if (M2.i0 >= 0) v = fmaf(xc[M2.i0], M2.w0, v);
            if (M2.i1 >= 0) v = fmaf(xc[M2.i1], M2.w1, v);
            if (M2.i2 >= 0) v = fmaf(xc[M2.i2], M2.w2, v);
            if (M2.i3 >= 0) v = fmaf(xc[M2.i3], M2.w3, v);
            sX[M2.dst] = v;
            sW[M2.dst] = wc[M2.wsrc];
        }
        __syncthreads();

#pragma unroll
        for (int n = 0; n < 9; ++n) {
            float wr[4], xr[4];
            *(float4*)wr = *(const float4*)&sW[n * 64 + tm4];
            *(float4*)xr = *(const float4*)&sX[n * 64 + tp4];
#pragma unroll
            for (int m = 0; m < 4; ++m)
#pragma unroll
                for (int p = 0; p < 4; ++p)
                    acc[m][p] = fmaf(wr[m], xr[p], acc[m][p]);
        }
        __syncthreads();
    }

    // ---------------- epilogue ----------------
#pragma unroll
    for (int m = 0; m < 4; ++m) {
        const int oc = tm4 + m;
        float4 v = make_float4(acc[m][0], acc[m][1], acc[m][2], acc[m][3]);
        *reinterpret_cast<float4*>(out + (((b * OC + oc) * HH + i) * WW + j0 + tp4)) = v;
    }
}

extern "C" void kernel_launch(void* const* d_in, const int* in_sizes, int n_in,
                              void* d_out, int out_size, void* d_ws, size_t ws_size,
                              hipStream_t stream) {
    const float* x  = (const float*)d_in[0];
    const float* Wp = (const float*)d_in[1];
    const float* bp = (const float*)d_in[2];
    const float* Wc = (const float*)d_in[3];
    float* out = (float*)d_out;
    dcn_fused<<<dim3((BB * HH * WW) / 64), dim3(256), 0, stream>>>(x, Wp, bp, Wc, out);
}